// Round 11
// baseline (531.405 us; speedup 1.0000x reference)
//
#include <hip/hip_runtime.h>
#include <hip/hip_fp16.h>
#include <hip/hip_cooperative_groups.h>
#include <math.h>

#define NN 50000
#define NE 800000

namespace cg = cooperative_groups;

static inline int ceil_div_h(int a, int b) { return (a + b - 1) / b; }

typedef _Float16 half8 __attribute__((ext_vector_type(8)));
typedef float f32x4 __attribute__((ext_vector_type(4)));

// ---------------- cooperative: weight convert + cursor zero + full CSR build ----------------
// Grid = 196 blocks x 256 (co-resident). Wt layout:
// [wt1 128x256 | wt2 128x128 | wtg1 256x128 | wtg2 128x256 | wtg3 64x64]
__global__ __launch_bounds__(256)
void build_all_kernel(const float* __restrict__ w1, const float* __restrict__ w2,
                      const float* __restrict__ g1w, const float* __restrict__ g2w,
                      const float* __restrict__ g3w, __half* __restrict__ wt,
                      const int* __restrict__ ei, int* __restrict__ cursor,
                      int* __restrict__ rowptr, int* __restrict__ bsum,
                      int* __restrict__ srcs) {
  cg::grid_group grid = cg::this_grid();
  const int tid = threadIdx.x;
  const int gidx = blockIdx.x * 256 + tid;   // 0..50175
  const int gsz = gridDim.x * 256;           // 50176
  __shared__ int tmp[256];

  // phase A: zero cursor + weight transpose/convert
  if (gidx < NN) cursor[gidx] = 0;
  for (int idx = gidx; idx < 118784; idx += gsz) {
    const float* W; int K, N, li;
    if (idx < 32768)        { W = w1;  K = 256; N = 128; li = idx; }
    else if (idx < 49152)   { W = w2;  K = 128; N = 128; li = idx - 32768; }
    else if (idx < 81920)   { W = g1w; K = 128; N = 256; li = idx - 49152; }
    else if (idx < 114688)  { W = g2w; K = 256; N = 128; li = idx - 81920; }
    else                    { W = g3w; K = 64;  N = 64;  li = idx - 114688; }
    int n = li / K, k = li - n * K;
    wt[idx] = __float2half_rn(W[(size_t)k * N + n]);
  }
  grid.sync();

  // phase B: histogram of dst
  for (int e = gidx; e < NE; e += gsz)
    atomicAdd(&cursor[ei[NE + e]], 1);
  grid.sync();

  // phase C: per-block exclusive scan of counts -> rowptr, block sums -> bsum
  {
    int v = (gidx < NN) ? cursor[gidx] : 0;
    tmp[tid] = v;
    __syncthreads();
    for (int off = 1; off < 256; off <<= 1) {
      int u = (tid >= off) ? tmp[tid - off] : 0;
      __syncthreads();
      tmp[tid] += u;
      __syncthreads();
    }
    if (gidx <= NN) rowptr[gidx] = tmp[tid] - v;
    if (tid == 255) bsum[blockIdx.x] = tmp[255];
  }
  grid.sync();

  // phase D: block 0 scans bsum (gridDim.x <= 256)
  if (blockIdx.x == 0) {
    int b = (tid < (int)gridDim.x) ? bsum[tid] : 0;
    tmp[tid] = b;
    __syncthreads();
    for (int off = 1; off < 256; off <<= 1) {
      int u = (tid >= off) ? tmp[tid - off] : 0;
      __syncthreads();
      tmp[tid] += u;
      __syncthreads();
    }
    if (tid < (int)gridDim.x) bsum[tid] = tmp[tid] - b;
  }
  grid.sync();

  // phase E: add block offsets; init cursor = rowptr
  if (gidx <= NN) {
    int val = rowptr[gidx] + bsum[blockIdx.x];
    rowptr[gidx] = val;
    if (gidx < NN) cursor[gidx] = val;
  }
  grid.sync();

  // phase F: scatter src indices grouped by dst
  for (int e = gidx; e < NE; e += gsz) {
    int s = ei[e], d = ei[NE + e];
    int pos = atomicAdd(&cursor[d], 1);
    srcs[pos] = s;
  }
}

// ---------------- fused MLP + GAT1 linear: x -> h1 -> h2 -> xh1 (+ scores) ----------------
// One block = 64 rows. h1/h2 live only in LDS. Phase 3 overlays its 256-row weight
// staging onto [Bs12|h1s] (h1s dead) -> 50.2 KB LDS total -> 3 blocks/CU.
__global__ __launch_bounds__(256)
void mlp_gat1_fused(const float* __restrict__ x,
                    const __half* __restrict__ wt1,   // [128][256]
                    const float* __restrict__ b1,
                    const __half* __restrict__ wt2,   // [128][128]
                    const float* __restrict__ b2,
                    const __half* __restrict__ wtg1,  // [256][128]
                    const float* __restrict__ a_src, const float* __restrict__ a_dst,
                    __half* __restrict__ xh1,
                    float* __restrict__ s_src, float* __restrict__ s_dst) {
  constexpr int SA = 40;    // staging stride in halves (80 B, 16B-aligned)
  constexpr int SH = 136;   // h-tile stride in halves (2-way bank alias = free)
  // layout (halves): As 2560 | Bs12 5120 | h1s 8704 | h2s 8704  = 25088 (50.2 KB)
  // phase 3 weight staging Bs3 = Bs12 start, 10240 halves (overlaps h1s).
  __shared__ __align__(16) _Float16 smem[25088];
  _Float16* As   = smem;
  _Float16* Bs12 = smem + 2560;
  _Float16* h1s  = smem + 7680;
  _Float16* h2s  = smem + 16384;
  _Float16* Bs3  = Bs12;
  const int tid = threadIdx.x;
  const int bm = blockIdx.x * 64;
  const int wave = tid >> 6, lane = tid & 63;
  const int l16 = lane & 15, quad = lane >> 4;
  const int wm = (wave & 1) * 32;     // phase 1/2: 2x2 wave layout, tile 32x64
  const int wn = (wave >> 1) * 64;

  // ---- phase 1: h1 = relu(x @ w1 + b1), [64x128], K=256 ----
  {
    f32x4 acc[2][4] = {};
    for (int k0 = 0; k0 < 256; k0 += 32) {
      #pragma unroll
      for (int i = 0; i < 2; ++i) {
        int idx = tid + i * 256;
        int m = idx >> 3, q = idx & 7;
        int gm = bm + m;
        float4 v = make_float4(0.f, 0.f, 0.f, 0.f);
        if (gm < NN) v = *(const float4*)&x[(size_t)gm * 256 + k0 + q * 4];
        union { __half2 h2[2]; float2 f2; } u;
        u.h2[0] = __floats2half2_rn(v.x, v.y);
        u.h2[1] = __floats2half2_rn(v.z, v.w);
        *(float2*)&As[m * SA + q * 4] = u.f2;
      }
      #pragma unroll
      for (int i = 0; i < 2; ++i) {
        int idx = tid + i * 256;
        int n = idx >> 2, kq = (idx & 3) * 8;
        *(float4*)&Bs12[n * SA + kq] = *(const float4*)&wt1[(size_t)n * 256 + k0 + kq];
      }
      __syncthreads();
      half8 af[2], bf[4];
      #pragma unroll
      for (int mi = 0; mi < 2; ++mi)
        af[mi] = *(const half8*)&As[(wm + mi * 16 + l16) * SA + quad * 8];
      #pragma unroll
      for (int ni = 0; ni < 4; ++ni)
        bf[ni] = *(const half8*)&Bs12[(wn + ni * 16 + l16) * SA + quad * 8];
      #pragma unroll
      for (int mi = 0; mi < 2; ++mi)
        #pragma unroll
        for (int ni = 0; ni < 4; ++ni)
          acc[mi][ni] = __builtin_amdgcn_mfma_f32_16x16x32_f16(af[mi], bf[ni], acc[mi][ni], 0, 0, 0);
      __syncthreads();
    }
    #pragma unroll
    for (int mi = 0; mi < 2; ++mi)
      #pragma unroll
      for (int r = 0; r < 4; ++r) {
        int row = wm + mi * 16 + quad * 4 + r;
        #pragma unroll
        for (int ni = 0; ni < 4; ++ni) {
          int col = wn + ni * 16 + l16;
          float v = acc[mi][ni][r] + b1[col];
          v = fmaxf(v, 0.f);
          h1s[row * SH + col] = (_Float16)v;
        }
      }
  }
  __syncthreads();

  // ---- phase 2: h2 = relu(h1 @ w2 + b2), [64x128], K=128, A from LDS ----
  {
    f32x4 acc[2][4] = {};
    for (int k0 = 0; k0 < 128; k0 += 32) {
      #pragma unroll
      for (int i = 0; i < 2; ++i) {
        int idx = tid + i * 256;
        int n = idx >> 2, kq = (idx & 3) * 8;
        *(float4*)&Bs12[n * SA + kq] = *(const float4*)&wt2[(size_t)n * 128 + k0 + kq];
      }
      __syncthreads();
      half8 af[2], bf[4];
      #pragma unroll
      for (int mi = 0; mi < 2; ++mi)
        af[mi] = *(const half8*)&h1s[(wm + mi * 16 + l16) * SH + k0 + quad * 8];
      #pragma unroll
      for (int ni = 0; ni < 4; ++ni)
        bf[ni] = *(const half8*)&Bs12[(wn + ni * 16 + l16) * SA + quad * 8];
      #pragma unroll
      for (int mi = 0; mi < 2; ++mi)
        #pragma unroll
        for (int ni = 0; ni < 4; ++ni)
          acc[mi][ni] = __builtin_amdgcn_mfma_f32_16x16x32_f16(af[mi], bf[ni], acc[mi][ni], 0, 0, 0);
      __syncthreads();
    }
    #pragma unroll
    for (int mi = 0; mi < 2; ++mi)
      #pragma unroll
      for (int r = 0; r < 4; ++r) {
        int row = wm + mi * 16 + quad * 4 + r;
        #pragma unroll
        for (int ni = 0; ni < 4; ++ni) {
          int col = wn + ni * 16 + l16;
          float v = acc[mi][ni][r] + b2[col];
          v = fmaxf(v, 0.f);
          h2s[row * SH + col] = (_Float16)v;
        }
      }
  }
  __syncthreads();

  // ---- phase 3: xh1 = h2 @ wg1, [64x256], K=128; wave = head; Bs3 overlays h1s ----
  {
    f32x4 acc[4][4] = {};
    const int wn3 = wave * 64;
    for (int k0 = 0; k0 < 128; k0 += 32) {
      #pragma unroll
      for (int i = 0; i < 4; ++i) {
        int idx = tid + i * 256;
        int n = idx >> 2, kq = (idx & 3) * 8;
        *(float4*)&Bs3[n * SA + kq] = *(const float4*)&wtg1[(size_t)n * 128 + k0 + kq];
      }
      __syncthreads();
      half8 af[4], bf[4];
      #pragma unroll
      for (int mi = 0; mi < 4; ++mi)
        af[mi] = *(const half8*)&h2s[(mi * 16 + l16) * SH + k0 + quad * 8];
      #pragma unroll
      for (int ni = 0; ni < 4; ++ni)
        bf[ni] = *(const half8*)&Bs3[(wn3 + ni * 16 + l16) * SA + quad * 8];
      #pragma unroll
      for (int mi = 0; mi < 4; ++mi)
        #pragma unroll
        for (int ni = 0; ni < 4; ++ni)
          acc[mi][ni] = __builtin_amdgcn_mfma_f32_16x16x32_f16(af[mi], bf[ni], acc[mi][ni], 0, 0, 0);
      __syncthreads();
    }
    // epilogue: store xh1 fp16 + fused scores (head h = wave)
    float asv[4], adv[4];
    #pragma unroll
    for (int ni = 0; ni < 4; ++ni) {
      int d = ni * 16 + l16;
      asv[ni] = a_src[wave * 64 + d];
      adv[ni] = a_dst[wave * 64 + d];
    }
    #pragma unroll
    for (int mi = 0; mi < 4; ++mi) {
      #pragma unroll
      for (int r = 0; r < 4; ++r) {
        int gm = bm + mi * 16 + quad * 4 + r;
        float ss = 0.f, sd = 0.f;
        #pragma unroll
        for (int ni = 0; ni < 4; ++ni) {
          float v = acc[mi][ni][r];
          ss = fmaf(v, asv[ni], ss);
          sd = fmaf(v, adv[ni], sd);
          if (gm < NN) xh1[(size_t)gm * 256 + wn3 + ni * 16 + l16] = __float2half_rn(v);
        }
        #pragma unroll
        for (int off = 1; off < 16; off <<= 1) {
          ss += __shfl_xor(ss, off, 64);
          sd += __shfl_xor(sd, off, 64);
        }
        if (l16 == 0 && gm < NN) {
          s_src[gm * 4 + wave] = ss;
          s_dst[gm * 4 + wave] = sd;
        }
      }
    }
  }
}

// ---------------- MFMA GEMM (GAT2/GAT3): C = act(A @ B + bias), optional fused scores ----
template<int BM, int TN, int WR, int WC, int ACT, int OUTH, int AF32, int HS>
__global__ __launch_bounds__(256)
void mfma_gemm(const void* __restrict__ Av, const __half* __restrict__ Bt,
               const float* __restrict__ bias, void* __restrict__ Cv,
               const float* __restrict__ a_src, const float* __restrict__ a_dst,
               float* __restrict__ s_src, float* __restrict__ s_dst,
               int M, int N, int K) {
  constexpr int FM = BM / WR / 16;
  constexpr int FN = TN / WC / 16;
  constexpr int SA = 40;
  __shared__ __align__(16) _Float16 As[BM * SA];
  __shared__ __align__(16) _Float16 Bs[TN * SA];
  const int tid = threadIdx.x;
  const int bm = blockIdx.y * BM, bn = blockIdx.x * TN;
  const int wave = tid >> 6, lane = tid & 63;
  const int wm = (wave % WR) * (BM / WR);
  const int wn = (wave / WR) * (TN / WC);
  const int l16 = lane & 15, quad = lane >> 4;

  f32x4 acc[FM][FN] = {};

  for (int k0 = 0; k0 < K; k0 += 32) {
    if (AF32) {
      const float* A = (const float*)Av;
      #pragma unroll
      for (int i = 0; i < (BM * 8) / 256; ++i) {
        int idx = tid + i * 256;
        int m = idx >> 3, q = idx & 7;
        int gm = bm + m;
        float4 v = make_float4(0.f, 0.f, 0.f, 0.f);
        if (gm < M) v = *(const float4*)&A[(size_t)gm * K + k0 + q * 4];
        union { __half2 h2[2]; float2 f2; } u;
        u.h2[0] = __floats2half2_rn(v.x, v.y);
        u.h2[1] = __floats2half2_rn(v.z, v.w);
        *(float2*)&As[m * SA + q * 4] = u.f2;
      }
    } else {
      const __half* A = (const __half*)Av;
      #pragma unroll
      for (int i = 0; i < (BM * 4) / 256; ++i) {
        int idx = tid + i * 256;
        int m = idx >> 2, q = (idx & 3) * 8;
        int gm = bm + m;
        float4 raw = make_float4(0.f, 0.f, 0.f, 0.f);
        if (gm < M) raw = *(const float4*)&A[(size_t)gm * K + k0 + q];
        *(float4*)&As[m * SA + q] = raw;
      }
    }
    #pragma unroll
    for (int i = 0; i < (TN * 4) / 256; ++i) {
      int idx = tid + i * 256;
      int n = idx >> 2, kq = (idx & 3) * 8;
      float4 raw = *(const float4*)&Bt[(size_t)(bn + n) * K + k0 + kq];
      *(float4*)&Bs[n * SA + kq] = raw;
    }
    __syncthreads();
    half8 af[FM], bf[FN];
    #pragma unroll
    for (int mi = 0; mi < FM; ++mi)
      af[mi] = *(const half8*)&As[(wm + mi * 16 + l16) * SA + quad * 8];
    #pragma unroll
    for (int ni = 0; ni < FN; ++ni)
      bf[ni] = *(const half8*)&Bs[(wn + ni * 16 + l16) * SA + quad * 8];
    #pragma unroll
    for (int mi = 0; mi < FM; ++mi)
      #pragma unroll
      for (int ni = 0; ni < FN; ++ni)
        acc[mi][ni] = __builtin_amdgcn_mfma_f32_16x16x32_f16(af[mi], bf[ni], acc[mi][ni], 0, 0, 0);
    __syncthreads();
  }

  #pragma unroll
  for (int mi = 0; mi < FM; ++mi) {
    #pragma unroll
    for (int r = 0; r < 4; ++r) {
      int gm = bm + wm + mi * 16 + quad * 4 + r;
      if (gm >= M) continue;
      #pragma unroll
      for (int ni = 0; ni < FN; ++ni) {
        int gn = bn + wn + ni * 16 + l16;
        float v = acc[mi][ni][r];
        if (bias) v += bias[gn];
        if (ACT == 1) v = fmaxf(v, 0.f);
        if (OUTH) ((__half*)Cv)[(size_t)gm * N + gn] = __float2half_rn(v);
        else      ((float*)Cv)[(size_t)gm * N + gn] = v;
      }
    }
  }

  if (HS > 0) {
    const int h = (bn + wn) >> 6;
    float asv[FN], adv[FN];
    #pragma unroll
    for (int ni = 0; ni < FN; ++ni) {
      int d = ni * 16 + l16;
      asv[ni] = a_src[h * 64 + d];
      adv[ni] = a_dst[h * 64 + d];
    }
    #pragma unroll
    for (int mi = 0; mi < FM; ++mi) {
      #pragma unroll
      for (int r = 0; r < 4; ++r) {
        float ss = 0.f, sd = 0.f;
        #pragma unroll
        for (int ni = 0; ni < FN; ++ni) {
          float v = acc[mi][ni][r];
          ss = fmaf(v, asv[ni], ss);
          sd = fmaf(v, adv[ni], sd);
        }
        #pragma unroll
        for (int off = 1; off < 16; off <<= 1) {
          ss += __shfl_xor(ss, off, 64);
          sd += __shfl_xor(sd, off, 64);
        }
        int gm = bm + wm + mi * 16 + quad * 4 + r;
        if (l16 == 0 && gm < M) {
          s_src[gm * HS + h] = ss;
          s_dst[gm * HS + h] = sd;
        }
      }
    }
  }
}

// ---------------- fused GAT aggregate (gather, fp16 features) ----------------
// MODE 0 = concat+bias+ELU -> fp16; 1 = mean(H=2)+bias+ELU -> fp16; 2 = +bias -> fp32.
template<int H, int MODE>
__global__ __launch_bounds__(256)
void gat_aggregate(const int* __restrict__ rowptr, const int* __restrict__ srcs,
                   const float* __restrict__ ssrc, const float* __restrict__ sdst,
                   const __half* __restrict__ xh, const float* __restrict__ bias,
                   void* __restrict__ outv) {
  constexpr int HD = H * 64;
  __shared__ float wbuf[4][64 * H];
  __shared__ int sbuf[4][64];
  const int wslot = threadIdx.x >> 6;
  const int wid = (blockIdx.x * blockDim.x + threadIdx.x) >> 6;
  const int lane = threadIdx.x & 63;
  if (wid >= NN) return;
  const int n = wid;
  const int start = rowptr[n];
  const int end = rowptr[n + 1];
  const int h = (lane * H) >> 6;

  float sdv[H];
  #pragma unroll
  for (int hh = 0; hh < H; ++hh) sdv[hh] = sdst[n * H + hh];

  float z;
  float acc[H];
  {
    float wself[H];
    #pragma unroll
    for (int hh = 0; hh < H; ++hh) {
      float e = ssrc[n * H + hh] + sdv[hh];
      e = e >= 0.f ? e : 0.2f * e;
      wself[hh] = __expf(e);
    }
    float ws = wself[h];
    z = ws;
    const __half* xr = xh + (size_t)n * HD + lane * H;
    if (H == 4) {
      float2 raw = *(const float2*)xr;
      __half2 p0 = *(__half2*)&raw.x;
      __half2 p1 = *(__half2*)&raw.y;
      float2 f0 = __half22float2(p0), f1 = __half22float2(p1);
      acc[0] = ws * f0.x; acc[1] = ws * f0.y; acc[2] = ws * f1.x; acc[3] = ws * f1.y;
    } else if (H == 2) {
      float2 f0 = __half22float2(*(const __half2*)xr);
      acc[0] = ws * f0.x; acc[1] = ws * f0.y;
    } else {
      acc[0] = ws * __half2float(xr[0]);
    }
  }

  for (int base = start; base < end; base += 64) {
    int cnt = end - base;
    if (cnt > 64) cnt = 64;
    if (lane < cnt) {
      int s = srcs[base + lane];
      sbuf[wslot][lane] = s;
      float ev[H];
      if (H == 4) {
        float4 t = *(const float4*)&ssrc[s * 4];
        ev[0] = t.x; ev[1] = t.y; ev[2] = t.z; ev[3] = t.w;
      } else if (H == 2) {
        float2 t = *(const float2*)&ssrc[s * 2];
        ev[0] = t.x; ev[1] = t.y;
      } else {
        ev[0] = ssrc[s];
      }
      #pragma unroll
      for (int hh = 0; hh < H; ++hh) {
        float e = ev[hh] + sdv[hh];
        e = e >= 0.f ? e : 0.2f * e;
        wbuf[wslot][lane * H + hh] = __expf(e);
      }
    }
    #pragma unroll 4
    for (int j = 0; j < cnt; ++j) {
      int s = sbuf[wslot][j];
      float w = wbuf[wslot][j * H + h];
      z += w;
      const __half* xr = xh + (size_t)s * HD + lane * H;
      if (H == 4) {
        float2 raw = *(const float2*)xr;
        __half2 p0 = *(__half2*)&raw.x;
        __half2 p1 = *(__half2*)&raw.y;
        float2 f0 = __half22float2(p0), f1 = __half22float2(p1);
        acc[0] = fmaf(w, f0.x, acc[0]); acc[1] = fmaf(w, f0.y, acc[1]);
        acc[2] = fmaf(w, f1.x, acc[2]); acc[3] = fmaf(w, f1.y, acc[3]);
      } else if (H == 2) {
        float2 f0 = __half22float2(*(const __half2*)xr);
        acc[0] = fmaf(w, f0.x, acc[0]); acc[1] = fmaf(w, f0.y, acc[1]);
      } else {
        acc[0] = fmaf(w, __half2float(xr[0]), acc[0]);
      }
    }
  }
  const float inv = 1.f / z;

  if (MODE == 0) {
    __half* out = (__half*)outv;
    float v[4];
    #pragma unroll
    for (int i = 0; i < 4; ++i) {
      v[i] = acc[i] * inv + bias[lane * 4 + i];
      v[i] = v[i] > 0.f ? v[i] : expm1f(v[i]);
    }
    union { __half2 h2[2]; float2 f2; } u;
    u.h2[0] = __floats2half2_rn(v[0], v[1]);
    u.h2[1] = __floats2half2_rn(v[2], v[3]);
    *(float2*)&out[(size_t)n * 256 + lane * 4] = u.f2;
  } else if (MODE == 1) {
    __half* out = (__half*)outv;
    float sv[2];
    #pragma unroll
    for (int i = 0; i < 2; ++i) {
      float mine = acc[i] * inv;
      float other = __shfl_xor(mine, 32, 64);
      sv[i] = (mine + other) * 0.5f;
    }
    if (lane < 32) {
      float v0 = sv[0] + bias[lane * 2 + 0];
      float v1 = sv[1] + bias[lane * 2 + 1];
      v0 = v0 > 0.f ? v0 : expm1f(v0);
      v1 = v1 > 0.f ? v1 : expm1f(v1);
      *(__half2*)&out[(size_t)n * 64 + lane * 2] = __floats2half2_rn(v0, v1);
    }
  } else {
    float* out = (float*)outv;
    out[(size_t)n * 64 + lane] = acc[0] * inv + bias[lane];
  }
}

// ---------------- orchestration ----------------

extern "C" void kernel_launch(void* const* d_in, const int* in_sizes, int n_in,
                              void* d_out, int out_size, void* d_ws, size_t ws_size,
                              hipStream_t stream) {
  const float* x    = (const float*)d_in[0];
  const int*   ei   = (const int*)d_in[1];
  const float* w1   = (const float*)d_in[2];
  const float* b1   = (const float*)d_in[3];
  const float* w2   = (const float*)d_in[4];
  const float* b2   = (const float*)d_in[5];
  const float* g1w  = (const float*)d_in[6];
  const float* g1as = (const float*)d_in[7];
  const float* g1ad = (const float*)d_in[8];
  const float* g1b  = (const float*)d_in[9];
  const float* g2w  = (const float*)d_in[10];
  const float* g2as = (const float*)d_in[11];
  const float* g2ad = (const float*)d_in[12];
  const float* g2b  = (const float*)d_in[13];
  const float* g3w  = (const float*)d_in[14];
  const float* g3as = (const float*)d_in[15];
  const float* g3ad = (const float*)d_in[16];
  const float* g3b  = (const float*)d_in[17];
  float* out = (float*)d_out;

  float* ws   = (float*)d_ws;
  float* bufA = ws;
  float* bufB = bufA + (size_t)NN * 256;
  float* bufC = bufB + (size_t)NN * 256;
  float* ssrc = bufC + (size_t)NN * 256;     // NN*4
  float* sdst = ssrc + (size_t)NN * 4;       // NN*4
  int* rowptr = (int*)(sdst + (size_t)NN * 4);  // NN+1
  int* cursor = rowptr + (NN + 1);              // NN
  int* bsum   = cursor + NN;                    // 256
  int* srcs   = bsum + 256;                     // NE
  __half* wt   = (__half*)(srcs + NE);          // 118784 halves
  __half* wt1  = wt;                            // 128x256
  __half* wt2  = wt + 32768;                    // 128x128
  __half* wtg1 = wt + 49152;                    // 256x128
  __half* wtg2 = wt + 81920;                    // 128x256
  __half* wtg3 = wt + 114688;                   // 64x64

  __half* xh1 = (__half*)bufC;   // NN*256
  __half* a1  = (__half*)bufA;   // NN*256
  __half* xh2 = (__half*)bufB;   // NN*128
  __half* a2  = (__half*)bufC;   // NN*64  (xh1 dead)
  __half* xh3 = (__half*)bufB;   // NN*64  (xh2 dead)

  const int TB = 256;
  const int grid_m = ceil_div_h(NN, 64);        // 782
  const int wgrid = ceil_div_h(NN, 4);

  // ---- cooperative: prep + CSR build (one kernel, 196 co-resident blocks) ----
  {
    void* args[] = {(void*)&w1, (void*)&w2, (void*)&g1w, (void*)&g2w, (void*)&g3w,
                    (void*)&wt, (void*)&ei, (void*)&cursor, (void*)&rowptr,
                    (void*)&bsum, (void*)&srcs};
    hipLaunchCooperativeKernel((void*)build_all_kernel, dim3(196), dim3(TB),
                               args, 0, stream);
  }

  // ---- fused MLP + GAT1 linear: x -> h1 -> h2 -> xh1 (+scores) ----
  mlp_gat1_fused<<<grid_m, TB, 0, stream>>>(x, wt1, b1, wt2, b2, wtg1,
                                            g1as, g1ad, xh1, ssrc, sdst);
  gat_aggregate<4, 0><<<wgrid, TB, 0, stream>>>(rowptr, srcs, ssrc, sdst, xh1, g1b, a1);

  // ---- GAT2: 256 -> 2x64, mean, ELU; scores fused ----
  mfma_gemm<64, 128, 2, 2, 0, 1, 0, 2><<<dim3(1, grid_m), TB, 0, stream>>>(
      a1, wtg2, nullptr, xh2, g2as, g2ad, ssrc, sdst, NN, 128, 256);
  gat_aggregate<2, 1><<<wgrid, TB, 0, stream>>>(rowptr, srcs, ssrc, sdst, xh2, g2b, a2);

  // ---- GAT3: 64 -> 1x64, identity mean, no ELU; scores fused ----
  mfma_gemm<64, 64, 4, 1, 0, 1, 0, 1><<<dim3(1, grid_m), TB, 0, stream>>>(
      a2, wtg3, nullptr, xh3, g3as, g3ad, ssrc, sdst, NN, 64, 64);
  gat_aggregate<1, 2><<<wgrid, TB, 0, stream>>>(rowptr, srcs, ssrc, sdst, xh3, g3b, out);
}

// Round 12
// 400.176 us; speedup vs baseline: 1.3279x; 1.3279x over previous
//
#include <hip/hip_runtime.h>
#include <hip/hip_fp16.h>
#include <math.h>

#define NN 50000
#define NE 800000

static inline int ceil_div_h(int a, int b) { return (a + b - 1) / b; }

typedef _Float16 half8 __attribute__((ext_vector_type(8)));
typedef float f32x4 __attribute__((ext_vector_type(4)));

// ---------------- prep: all weight transposes + fp16 convert + cursor zero ----------------
// Wt layout: [wt1 128x256 | wt2 128x128 | wtg1 256x128 | wtg2 128x256 | wtg3 64x64]
__global__ __launch_bounds__(256)
void prep_kernel(const float* __restrict__ w1, const float* __restrict__ w2,
                 const float* __restrict__ g1w, const float* __restrict__ g2w,
                 const float* __restrict__ g3w, __half* __restrict__ wt,
                 int* __restrict__ cursor) {
  int idx = blockIdx.x * 256 + threadIdx.x;
  if (idx < NN) cursor[idx] = 0;
  const float* W; int K, N, li;
  if (idx < 32768)        { W = w1;  K = 256; N = 128; li = idx; }
  else if (idx < 49152)   { W = w2;  K = 128; N = 128; li = idx - 32768; }
  else if (idx < 81920)   { W = g1w; K = 128; N = 256; li = idx - 49152; }
  else if (idx < 114688)  { W = g2w; K = 256; N = 128; li = idx - 81920; }
  else if (idx < 118784)  { W = g3w; K = 64;  N = 64;  li = idx - 114688; }
  else return;
  int n = li / K, k = li - n * K;
  wt[idx] = __float2half_rn(W[(size_t)k * N + n]);
}

// ---------------- fused MLP + GAT1 linear: x -> h1 -> h2 -> xh1 (+ scores) ----------------
// One block = 64 rows. h1/h2 live only in LDS. Phase 3 overlays its 256-row weight
// staging onto [Bs12|h1s] (h1s dead) -> 50.2 KB LDS total -> 3 blocks/CU.
__global__ __launch_bounds__(256)
void mlp_gat1_fused(const float* __restrict__ x,
                    const __half* __restrict__ wt1,   // [128][256]
                    const float* __restrict__ b1,
                    const __half* __restrict__ wt2,   // [128][128]
                    const float* __restrict__ b2,
                    const __half* __restrict__ wtg1,  // [256][128]
                    const float* __restrict__ a_src, const float* __restrict__ a_dst,
                    __half* __restrict__ xh1,
                    float* __restrict__ s_src, float* __restrict__ s_dst) {
  constexpr int SA = 40;    // staging stride in halves (80 B, 16B-aligned)
  constexpr int SH = 136;   // h-tile stride in halves (2-way bank alias = free)
  // layout (halves): As 2560 | Bs12 5120 | h1s 8704 | h2s 8704  = 25088 (50.2 KB)
  // phase 3 weight staging Bs3 = Bs12 start, 10240 halves (overlaps h1s).
  __shared__ __align__(16) _Float16 smem[25088];
  _Float16* As   = smem;
  _Float16* Bs12 = smem + 2560;
  _Float16* h1s  = smem + 7680;
  _Float16* h2s  = smem + 16384;
  _Float16* Bs3  = Bs12;
  const int tid = threadIdx.x;
  const int bm = blockIdx.x * 64;
  const int wave = tid >> 6, lane = tid & 63;
  const int l16 = lane & 15, quad = lane >> 4;
  const int wm = (wave & 1) * 32;     // phase 1/2: 2x2 wave layout, tile 32x64
  const int wn = (wave >> 1) * 64;

  // ---- phase 1: h1 = relu(x @ w1 + b1), [64x128], K=256 ----
  {
    f32x4 acc[2][4] = {};
    for (int k0 = 0; k0 < 256; k0 += 32) {
      #pragma unroll
      for (int i = 0; i < 2; ++i) {
        int idx = tid + i * 256;
        int m = idx >> 3, q = idx & 7;
        int gm = bm + m;
        float4 v = make_float4(0.f, 0.f, 0.f, 0.f);
        if (gm < NN) v = *(const float4*)&x[(size_t)gm * 256 + k0 + q * 4];
        union { __half2 h2[2]; float2 f2; } u;
        u.h2[0] = __floats2half2_rn(v.x, v.y);
        u.h2[1] = __floats2half2_rn(v.z, v.w);
        *(float2*)&As[m * SA + q * 4] = u.f2;
      }
      #pragma unroll
      for (int i = 0; i < 2; ++i) {
        int idx = tid + i * 256;
        int n = idx >> 2, kq = (idx & 3) * 8;
        *(float4*)&Bs12[n * SA + kq] = *(const float4*)&wt1[(size_t)n * 256 + k0 + kq];
      }
      __syncthreads();
      half8 af[2], bf[4];
      #pragma unroll
      for (int mi = 0; mi < 2; ++mi)
        af[mi] = *(const half8*)&As[(wm + mi * 16 + l16) * SA + quad * 8];
      #pragma unroll
      for (int ni = 0; ni < 4; ++ni)
        bf[ni] = *(const half8*)&Bs12[(wn + ni * 16 + l16) * SA + quad * 8];
      #pragma unroll
      for (int mi = 0; mi < 2; ++mi)
        #pragma unroll
        for (int ni = 0; ni < 4; ++ni)
          acc[mi][ni] = __builtin_amdgcn_mfma_f32_16x16x32_f16(af[mi], bf[ni], acc[mi][ni], 0, 0, 0);
      __syncthreads();
    }
    #pragma unroll
    for (int mi = 0; mi < 2; ++mi)
      #pragma unroll
      for (int r = 0; r < 4; ++r) {
        int row = wm + mi * 16 + quad * 4 + r;
        #pragma unroll
        for (int ni = 0; ni < 4; ++ni) {
          int col = wn + ni * 16 + l16;
          float v = acc[mi][ni][r] + b1[col];
          v = fmaxf(v, 0.f);
          h1s[row * SH + col] = (_Float16)v;
        }
      }
  }
  __syncthreads();

  // ---- phase 2: h2 = relu(h1 @ w2 + b2), [64x128], K=128, A from LDS ----
  {
    f32x4 acc[2][4] = {};
    for (int k0 = 0; k0 < 128; k0 += 32) {
      #pragma unroll
      for (int i = 0; i < 2; ++i) {
        int idx = tid + i * 256;
        int n = idx >> 2, kq = (idx & 3) * 8;
        *(float4*)&Bs12[n * SA + kq] = *(const float4*)&wt2[(size_t)n * 128 + k0 + kq];
      }
      __syncthreads();
      half8 af[2], bf[4];
      #pragma unroll
      for (int mi = 0; mi < 2; ++mi)
        af[mi] = *(const half8*)&h1s[(wm + mi * 16 + l16) * SH + k0 + quad * 8];
      #pragma unroll
      for (int ni = 0; ni < 4; ++ni)
        bf[ni] = *(const half8*)&Bs12[(wn + ni * 16 + l16) * SA + quad * 8];
      #pragma unroll
      for (int mi = 0; mi < 2; ++mi)
        #pragma unroll
        for (int ni = 0; ni < 4; ++ni)
          acc[mi][ni] = __builtin_amdgcn_mfma_f32_16x16x32_f16(af[mi], bf[ni], acc[mi][ni], 0, 0, 0);
      __syncthreads();
    }
    #pragma unroll
    for (int mi = 0; mi < 2; ++mi)
      #pragma unroll
      for (int r = 0; r < 4; ++r) {
        int row = wm + mi * 16 + quad * 4 + r;
        #pragma unroll
        for (int ni = 0; ni < 4; ++ni) {
          int col = wn + ni * 16 + l16;
          float v = acc[mi][ni][r] + b2[col];
          v = fmaxf(v, 0.f);
          h2s[row * SH + col] = (_Float16)v;
        }
      }
  }
  __syncthreads();

  // ---- phase 3: xh1 = h2 @ wg1, [64x256], K=128; wave = head; Bs3 overlays h1s ----
  {
    f32x4 acc[4][4] = {};
    const int wn3 = wave * 64;
    for (int k0 = 0; k0 < 128; k0 += 32) {
      #pragma unroll
      for (int i = 0; i < 4; ++i) {
        int idx = tid + i * 256;
        int n = idx >> 2, kq = (idx & 3) * 8;
        *(float4*)&Bs3[n * SA + kq] = *(const float4*)&wtg1[(size_t)n * 128 + k0 + kq];
      }
      __syncthreads();
      half8 af[4], bf[4];
      #pragma unroll
      for (int mi = 0; mi < 4; ++mi)
        af[mi] = *(const half8*)&h2s[(mi * 16 + l16) * SH + k0 + quad * 8];
      #pragma unroll
      for (int ni = 0; ni < 4; ++ni)
        bf[ni] = *(const half8*)&Bs3[(wn3 + ni * 16 + l16) * SA + quad * 8];
      #pragma unroll
      for (int mi = 0; mi < 4; ++mi)
        #pragma unroll
        for (int ni = 0; ni < 4; ++ni)
          acc[mi][ni] = __builtin_amdgcn_mfma_f32_16x16x32_f16(af[mi], bf[ni], acc[mi][ni], 0, 0, 0);
      __syncthreads();
    }
    // epilogue: store xh1 fp16 + fused scores (head h = wave)
    float asv[4], adv[4];
    #pragma unroll
    for (int ni = 0; ni < 4; ++ni) {
      int d = ni * 16 + l16;
      asv[ni] = a_src[wave * 64 + d];
      adv[ni] = a_dst[wave * 64 + d];
    }
    #pragma unroll
    for (int mi = 0; mi < 4; ++mi) {
      #pragma unroll
      for (int r = 0; r < 4; ++r) {
        int gm = bm + mi * 16 + quad * 4 + r;
        float ss = 0.f, sd = 0.f;
        #pragma unroll
        for (int ni = 0; ni < 4; ++ni) {
          float v = acc[mi][ni][r];
          ss = fmaf(v, asv[ni], ss);
          sd = fmaf(v, adv[ni], sd);
          if (gm < NN) xh1[(size_t)gm * 256 + wn3 + ni * 16 + l16] = __float2half_rn(v);
        }
        #pragma unroll
        for (int off = 1; off < 16; off <<= 1) {
          ss += __shfl_xor(ss, off, 64);
          sd += __shfl_xor(sd, off, 64);
        }
        if (l16 == 0 && gm < NN) {
          s_src[gm * 4 + wave] = ss;
          s_dst[gm * 4 + wave] = sd;
        }
      }
    }
  }
}

// ---------------- MFMA GEMM (GAT2/GAT3): C = act(A @ B + bias), optional fused scores ----
template<int BM, int TN, int WR, int WC, int ACT, int OUTH, int AF32, int HS>
__global__ __launch_bounds__(256)
void mfma_gemm(const void* __restrict__ Av, const __half* __restrict__ Bt,
               const float* __restrict__ bias, void* __restrict__ Cv,
               const float* __restrict__ a_src, const float* __restrict__ a_dst,
               float* __restrict__ s_src, float* __restrict__ s_dst,
               int M, int N, int K) {
  constexpr int FM = BM / WR / 16;
  constexpr int FN = TN / WC / 16;
  constexpr int SA = 40;
  __shared__ __align__(16) _Float16 As[BM * SA];
  __shared__ __align__(16) _Float16 Bs[TN * SA];
  const int tid = threadIdx.x;
  const int bm = blockIdx.y * BM, bn = blockIdx.x * TN;
  const int wave = tid >> 6, lane = tid & 63;
  const int wm = (wave % WR) * (BM / WR);
  const int wn = (wave / WR) * (TN / WC);
  const int l16 = lane & 15, quad = lane >> 4;

  f32x4 acc[FM][FN] = {};

  for (int k0 = 0; k0 < K; k0 += 32) {
    if (AF32) {
      const float* A = (const float*)Av;
      #pragma unroll
      for (int i = 0; i < (BM * 8) / 256; ++i) {
        int idx = tid + i * 256;
        int m = idx >> 3, q = idx & 7;
        int gm = bm + m;
        float4 v = make_float4(0.f, 0.f, 0.f, 0.f);
        if (gm < M) v = *(const float4*)&A[(size_t)gm * K + k0 + q * 4];
        union { __half2 h2[2]; float2 f2; } u;
        u.h2[0] = __floats2half2_rn(v.x, v.y);
        u.h2[1] = __floats2half2_rn(v.z, v.w);
        *(float2*)&As[m * SA + q * 4] = u.f2;
      }
    } else {
      const __half* A = (const __half*)Av;
      #pragma unroll
      for (int i = 0; i < (BM * 4) / 256; ++i) {
        int idx = tid + i * 256;
        int m = idx >> 2, q = (idx & 3) * 8;
        int gm = bm + m;
        float4 raw = make_float4(0.f, 0.f, 0.f, 0.f);
        if (gm < M) raw = *(const float4*)&A[(size_t)gm * K + k0 + q];
        *(float4*)&As[m * SA + q] = raw;
      }
    }
    #pragma unroll
    for (int i = 0; i < (TN * 4) / 256; ++i) {
      int idx = tid + i * 256;
      int n = idx >> 2, kq = (idx & 3) * 8;
      float4 raw = *(const float4*)&Bt[(size_t)(bn + n) * K + k0 + kq];
      *(float4*)&Bs[n * SA + kq] = raw;
    }
    __syncthreads();
    half8 af[FM], bf[FN];
    #pragma unroll
    for (int mi = 0; mi < FM; ++mi)
      af[mi] = *(const half8*)&As[(wm + mi * 16 + l16) * SA + quad * 8];
    #pragma unroll
    for (int ni = 0; ni < FN; ++ni)
      bf[ni] = *(const half8*)&Bs[(wn + ni * 16 + l16) * SA + quad * 8];
    #pragma unroll
    for (int mi = 0; mi < FM; ++mi)
      #pragma unroll
      for (int ni = 0; ni < FN; ++ni)
        acc[mi][ni] = __builtin_amdgcn_mfma_f32_16x16x32_f16(af[mi], bf[ni], acc[mi][ni], 0, 0, 0);
    __syncthreads();
  }

  #pragma unroll
  for (int mi = 0; mi < FM; ++mi) {
    #pragma unroll
    for (int r = 0; r < 4; ++r) {
      int gm = bm + wm + mi * 16 + quad * 4 + r;
      if (gm >= M) continue;
      #pragma unroll
      for (int ni = 0; ni < FN; ++ni) {
        int gn = bn + wn + ni * 16 + l16;
        float v = acc[mi][ni][r];
        if (bias) v += bias[gn];
        if (ACT == 1) v = fmaxf(v, 0.f);
        if (OUTH) ((__half*)Cv)[(size_t)gm * N + gn] = __float2half_rn(v);
        else      ((float*)Cv)[(size_t)gm * N + gn] = v;
      }
    }
  }

  if (HS > 0) {
    const int h = (bn + wn) >> 6;
    float asv[FN], adv[FN];
    #pragma unroll
    for (int ni = 0; ni < FN; ++ni) {
      int d = ni * 16 + l16;
      asv[ni] = a_src[h * 64 + d];
      adv[ni] = a_dst[h * 64 + d];
    }
    #pragma unroll
    for (int mi = 0; mi < FM; ++mi) {
      #pragma unroll
      for (int r = 0; r < 4; ++r) {
        float ss = 0.f, sd = 0.f;
        #pragma unroll
        for (int ni = 0; ni < FN; ++ni) {
          float v = acc[mi][ni][r];
          ss = fmaf(v, asv[ni], ss);
          sd = fmaf(v, adv[ni], sd);
        }
        #pragma unroll
        for (int off = 1; off < 16; off <<= 1) {
          ss += __shfl_xor(ss, off, 64);
          sd += __shfl_xor(sd, off, 64);
        }
        int gm = bm + wm + mi * 16 + quad * 4 + r;
        if (l16 == 0 && gm < M) {
          s_src[gm * HS + h] = ss;
          s_dst[gm * HS + h] = sd;
        }
      }
    }
  }
}

// ---------------- CSR build over the NE real edges ----------------

__global__ __launch_bounds__(256)
void hist_kernel(const int* __restrict__ ei, int* __restrict__ cnt) {
  int e = blockIdx.x * blockDim.x + threadIdx.x;
  if (e >= NE) return;
  atomicAdd(&cnt[ei[NE + e]], 1);
}

__global__ __launch_bounds__(256)
void scan1_kernel(const int* __restrict__ in, int* __restrict__ out,
                  int* __restrict__ bsum, int n) {
  __shared__ int tmp[256];
  int t = threadIdx.x;
  int i = blockIdx.x * 256 + t;
  int v = (i < n) ? in[i] : 0;
  tmp[t] = v;
  __syncthreads();
  for (int off = 1; off < 256; off <<= 1) {
    int u = (t >= off) ? tmp[t - off] : 0;
    __syncthreads();
    tmp[t] += u;
    __syncthreads();
  }
  if (i <= n) out[i] = tmp[t] - v;
  if (t == 255) bsum[blockIdx.x] = tmp[255];
}

__global__ __launch_bounds__(256)
void scan2_kernel(int* __restrict__ data, int n) {
  __shared__ int tmp[256];
  int t = threadIdx.x;
  int v = (t < n) ? data[t] : 0;
  tmp[t] = v;
  __syncthreads();
  for (int off = 1; off < 256; off <<= 1) {
    int u = (t >= off) ? tmp[t - off] : 0;
    __syncthreads();
    tmp[t] += u;
    __syncthreads();
  }
  if (t < n) data[t] = tmp[t] - v;
}

__global__ __launch_bounds__(256)
void scan3_kernel(int* __restrict__ out, const int* __restrict__ bsum,
                  int* __restrict__ cursor, int n) {
  int i = blockIdx.x * 256 + threadIdx.x;
  if (i > n) return;
  int v = out[i] + bsum[blockIdx.x];
  out[i] = v;
  if (i < n) cursor[i] = v;
}

__global__ __launch_bounds__(256)
void scatter_kernel(const int* __restrict__ ei, int* __restrict__ cursor,
                    int* __restrict__ srcs) {
  int e = blockIdx.x * blockDim.x + threadIdx.x;
  if (e >= NE) return;
  int s = ei[e], d = ei[NE + e];
  int pos = atomicAdd(&cursor[d], 1);
  srcs[pos] = s;
}

// ---------------- fused GAT aggregate (gather, fp16 features) ----------------
// MODE 0 = concat+bias+ELU -> fp16; 1 = mean(H=2)+bias+ELU -> fp16; 2 = +bias -> fp32.
template<int H, int MODE>
__global__ __launch_bounds__(256)
void gat_aggregate(const int* __restrict__ rowptr, const int* __restrict__ srcs,
                   const float* __restrict__ ssrc, const float* __restrict__ sdst,
                   const __half* __restrict__ xh, const float* __restrict__ bias,
                   void* __restrict__ outv) {
  constexpr int HD = H * 64;
  __shared__ float wbuf[4][64 * H];
  __shared__ int sbuf[4][64];
  const int wslot = threadIdx.x >> 6;
  const int wid = (blockIdx.x * blockDim.x + threadIdx.x) >> 6;
  const int lane = threadIdx.x & 63;
  if (wid >= NN) return;
  const int n = wid;
  const int start = rowptr[n];
  const int end = rowptr[n + 1];
  const int h = (lane * H) >> 6;

  float sdv[H];
  #pragma unroll
  for (int hh = 0; hh < H; ++hh) sdv[hh] = sdst[n * H + hh];

  float z;
  float acc[H];
  {
    float wself[H];
    #pragma unroll
    for (int hh = 0; hh < H; ++hh) {
      float e = ssrc[n * H + hh] + sdv[hh];
      e = e >= 0.f ? e : 0.2f * e;
      wself[hh] = __expf(e);
    }
    float ws = wself[h];
    z = ws;
    const __half* xr = xh + (size_t)n * HD + lane * H;
    if (H == 4) {
      float2 raw = *(const float2*)xr;
      __half2 p0 = *(__half2*)&raw.x;
      __half2 p1 = *(__half2*)&raw.y;
      float2 f0 = __half22float2(p0), f1 = __half22float2(p1);
      acc[0] = ws * f0.x; acc[1] = ws * f0.y; acc[2] = ws * f1.x; acc[3] = ws * f1.y;
    } else if (H == 2) {
      float2 f0 = __half22float2(*(const __half2*)xr);
      acc[0] = ws * f0.x; acc[1] = ws * f0.y;
    } else {
      acc[0] = ws * __half2float(xr[0]);
    }
  }

  for (int base = start; base < end; base += 64) {
    int cnt = end - base;
    if (cnt > 64) cnt = 64;
    if (lane < cnt) {
      int s = srcs[base + lane];
      sbuf[wslot][lane] = s;
      float ev[H];
      if (H == 4) {
        float4 t = *(const float4*)&ssrc[s * 4];
        ev[0] = t.x; ev[1] = t.y; ev[2] = t.z; ev[3] = t.w;
      } else if (H == 2) {
        float2 t = *(const float2*)&ssrc[s * 2];
        ev[0] = t.x; ev[1] = t.y;
      } else {
        ev[0] = ssrc[s];
      }
      #pragma unroll
      for (int hh = 0; hh < H; ++hh) {
        float e = ev[hh] + sdv[hh];
        e = e >= 0.f ? e : 0.2f * e;
        wbuf[wslot][lane * H + hh] = __expf(e);
      }
    }
    #pragma unroll 4
    for (int j = 0; j < cnt; ++j) {
      int s = sbuf[wslot][j];
      float w = wbuf[wslot][j * H + h];
      z += w;
      const __half* xr = xh + (size_t)s * HD + lane * H;
      if (H == 4) {
        float2 raw = *(const float2*)xr;
        __half2 p0 = *(__half2*)&raw.x;
        __half2 p1 = *(__half2*)&raw.y;
        float2 f0 = __half22float2(p0), f1 = __half22float2(p1);
        acc[0] = fmaf(w, f0.x, acc[0]); acc[1] = fmaf(w, f0.y, acc[1]);
        acc[2] = fmaf(w, f1.x, acc[2]); acc[3] = fmaf(w, f1.y, acc[3]);
      } else if (H == 2) {
        float2 f0 = __half22float2(*(const __half2*)xr);
        acc[0] = fmaf(w, f0.x, acc[0]); acc[1] = fmaf(w, f0.y, acc[1]);
      } else {
        acc[0] = fmaf(w, __half2float(xr[0]), acc[0]);
      }
    }
  }
  const float inv = 1.f / z;

  if (MODE == 0) {
    __half* out = (__half*)outv;
    float v[4];
    #pragma unroll
    for (int i = 0; i < 4; ++i) {
      v[i] = acc[i] * inv + bias[lane * 4 + i];
      v[i] = v[i] > 0.f ? v[i] : expm1f(v[i]);
    }
    union { __half2 h2[2]; float2 f2; } u;
    u.h2[0] = __floats2half2_rn(v[0], v[1]);
    u.h2[1] = __floats2half2_rn(v[2], v[3]);
    *(float2*)&out[(size_t)n * 256 + lane * 4] = u.f2;
  } else if (MODE == 1) {
    __half* out = (__half*)outv;
    float sv[2];
    #pragma unroll
    for (int i = 0; i < 2; ++i) {
      float mine = acc[i] * inv;
      float other = __shfl_xor(mine, 32, 64);
      sv[i] = (mine + other) * 0.5f;
    }
    if (lane < 32) {
      float v0 = sv[0] + bias[lane * 2 + 0];
      float v1 = sv[1] + bias[lane * 2 + 1];
      v0 = v0 > 0.f ? v0 : expm1f(v0);
      v1 = v1 > 0.f ? v1 : expm1f(v1);
      *(__half2*)&out[(size_t)n * 64 + lane * 2] = __floats2half2_rn(v0, v1);
    }
  } else {
    float* out = (float*)outv;
    out[(size_t)n * 64 + lane] = acc[0] * inv + bias[lane];
  }
}

// ---------------- orchestration ----------------

extern "C" void kernel_launch(void* const* d_in, const int* in_sizes, int n_in,
                              void* d_out, int out_size, void* d_ws, size_t ws_size,
                              hipStream_t stream) {
  const float* x    = (const float*)d_in[0];
  const int*   ei   = (const int*)d_in[1];
  const float* w1   = (const float*)d_in[2];
  const float* b1   = (const float*)d_in[3];
  const float* w2   = (const float*)d_in[4];
  const float* b2   = (const float*)d_in[5];
  const float* g1w  = (const float*)d_in[6];
  const float* g1as = (const float*)d_in[7];
  const float* g1ad = (const float*)d_in[8];
  const float* g1b  = (const float*)d_in[9];
  const float* g2w  = (const float*)d_in[10];
  const float* g2as = (const float*)d_in[11];
  const float* g2ad = (const float*)d_in[12];
  const float* g2b  = (const float*)d_in[13];
  const float* g3w  = (const float*)d_in[14];
  const float* g3as = (const float*)d_in[15];
  const float* g3ad = (const float*)d_in[16];
  const float* g3b  = (const float*)d_in[17];
  float* out = (float*)d_out;

  float* ws   = (float*)d_ws;
  float* bufA = ws;
  float* bufB = bufA + (size_t)NN * 256;
  float* bufC = bufB + (size_t)NN * 256;
  float* ssrc = bufC + (size_t)NN * 256;     // NN*4
  float* sdst = ssrc + (size_t)NN * 4;       // NN*4
  int* rowptr = (int*)(sdst + (size_t)NN * 4);  // NN+1
  int* cursor = rowptr + (NN + 1);              // NN
  int* bsum   = cursor + NN;                    // 256
  int* srcs   = bsum + 256;                     // NE
  __half* wt   = (__half*)(srcs + NE);          // 118784 halves
  __half* wt1  = wt;                            // 128x256
  __half* wt2  = wt + 32768;                    // 128x128
  __half* wtg1 = wt + 49152;                    // 256x128
  __half* wtg2 = wt + 81920;                    // 128x256
  __half* wtg3 = wt + 114688;                   // 64x64

  __half* xh1 = (__half*)bufC;   // NN*256
  __half* a1  = (__half*)bufA;   // NN*256
  __half* xh2 = (__half*)bufB;   // NN*128
  __half* a2  = (__half*)bufC;   // NN*64  (xh1 dead)
  __half* xh3 = (__half*)bufB;   // NN*64  (xh2 dead)

  const int TB = 256;
  const int grid_m = ceil_div_h(NN, 64);        // 782
  const int egrid = ceil_div_h(NE, TB);
  const int sgrid = ceil_div_h(NN + 1, TB);
  const int wgrid = ceil_div_h(NN, 4);

  // ---- prep: weight convert + cursor zero ----
  prep_kernel<<<ceil_div_h(118784, TB), TB, 0, stream>>>(w1, w2, g1w, g2w, g3w, wt, cursor);

  // ---- CSR build (separate kernels: full oversubscription for hist/scatter) ----
  hist_kernel<<<egrid, TB, 0, stream>>>(ei, cursor);
  scan1_kernel<<<sgrid, TB, 0, stream>>>(cursor, rowptr, bsum, NN);
  scan2_kernel<<<1, TB, 0, stream>>>(bsum, sgrid);
  scan3_kernel<<<sgrid, TB, 0, stream>>>(rowptr, bsum, cursor, NN);
  scatter_kernel<<<egrid, TB, 0, stream>>>(ei, cursor, srcs);

  // ---- fused MLP + GAT1 linear: x -> h1 -> h2 -> xh1 (+scores) ----
  mlp_gat1_fused<<<grid_m, TB, 0, stream>>>(x, wt1, b1, wt2, b2, wtg1,
                                            g1as, g1ad, xh1, ssrc, sdst);
  gat_aggregate<4, 0><<<wgrid, TB, 0, stream>>>(rowptr, srcs, ssrc, sdst, xh1, g1b, a1);

  // ---- GAT2: 256 -> 2x64, mean, ELU; scores fused ----
  mfma_gemm<64, 128, 2, 2, 0, 1, 0, 2><<<dim3(1, grid_m), TB, 0, stream>>>(
      a1, wtg2, nullptr, xh2, g2as, g2ad, ssrc, sdst, NN, 128, 256);
  gat_aggregate<2, 1><<<wgrid, TB, 0, stream>>>(rowptr, srcs, ssrc, sdst, xh2, g2b, a2);

  // ---- GAT3: 64 -> 1x64, identity mean, no ELU; scores fused ----
  mfma_gemm<64, 64, 4, 1, 0, 1, 0, 1><<<dim3(1, grid_m), TB, 0, stream>>>(
      a2, wtg3, nullptr, xh3, g3as, g3ad, ssrc, sdst, NN, 64, 64);
  gat_aggregate<1, 2><<<wgrid, TB, 0, stream>>>(rowptr, srcs, ssrc, sdst, xh3, g3b, out);
}